// Round 4
// baseline (286.794 us; speedup 1.0000x reference)
//
#include <hip/hip_runtime.h>
#include <math.h>

constexpr int B_ = 4096, T_ = 200, D_ = 64, NT = 256;
constexpr float NEG_INF_F = -4294967295.0f;  // float32(-2^32+1)

typedef __attribute__((ext_vector_type(8))) __bf16 bf16x8;
typedef __attribute__((ext_vector_type(4))) float f32x4;

__device__ __host__ inline unsigned short f2b_rne(float x) {
    unsigned u = __builtin_bit_cast(unsigned, x);
    u += 0x7FFF + ((u >> 16) & 1);
    return (unsigned short)(u >> 16);
}

__device__ inline unsigned short b16bits(float x) {
    return __builtin_bit_cast(unsigned short, (__bf16)x);
}

__device__ inline bf16x8 pack8(float4 lo, float4 hi) {
    bf16x8 r;
    r[0] = (__bf16)lo.x; r[1] = (__bf16)lo.y; r[2] = (__bf16)lo.z; r[3] = (__bf16)lo.w;
    r[4] = (__bf16)hi.x; r[5] = (__bf16)hi.y; r[6] = (__bf16)hi.z; r[7] = (__bf16)hi.w;
    return r;
}

__device__ inline bf16x8 pack8m(float4 lo, float4 hi, float4 ql, float4 qh) {
    bf16x8 r;
    r[0] = (__bf16)(lo.x * ql.x); r[1] = (__bf16)(lo.y * ql.y);
    r[2] = (__bf16)(lo.z * ql.z); r[3] = (__bf16)(lo.w * ql.w);
    r[4] = (__bf16)(hi.x * qh.x); r[5] = (__bf16)(hi.y * qh.y);
    r[6] = (__bf16)(hi.z * qh.z); r[7] = (__bf16)(hi.w * qh.w);
    return r;
}

// ---------------------------------------------------------------------------
// Fold weights into MFMA-fragment order (bf16). Same layouts as round 3.
// ---------------------------------------------------------------------------
__global__ void fold_weights(const float* __restrict__ W1,
                             const float* __restrict__ W2,
                             unsigned short* __restrict__ w1f,
                             unsigned short* __restrict__ w2f,
                             float* __restrict__ wqf) {
    int i = blockIdx.x * blockDim.x + threadIdx.x;
    if (i < 10240) {
        int j = i & 7, lane = (i >> 3) & 63, nt = (i >> 9) % 5, s = i / 2560;
        int k = s * 32 + (lane >> 4) * 8 + j;
        int n = nt * 16 + (lane & 15);
        float v = (k < 64) ? W1[(64 + k) * 80 + n] - W1[(128 + k) * 80 + n]
                           : W1[(192 + (k - 64)) * 80 + n];
        w1f[i] = f2b_rne(v);
    } else if (i < 14848) {
        int i2 = i - 10240;
        int j = i2 & 7, lane = (i2 >> 3) & 63, nt = (i2 >> 9) % 3, s = i2 / 1536;
        int k = s * 32 + (lane >> 4) * 8 + j;
        int n = nt * 16 + (lane & 15);
        float v = (k < 80 && n < 40) ? W2[k * 40 + n] : 0.f;
        w2f[i2] = f2b_rne(v);
    } else if (i < 19968) {
        int i3 = i - 14848;
        int n = i3 % 80, d = i3 / 80;
        wqf[i3] = W1[d * 80 + n] + W1[(128 + d) * 80 + n];
    }
}

__global__ __launch_bounds__(256)
void hinit_kernel(const float* __restrict__ q, const float* __restrict__ wqf,
                  const float* __restrict__ b1, float* __restrict__ hinit) {
    int i = blockIdx.x * blockDim.x + threadIdx.x;
    if (i >= B_ * 80) return;
    int b = i / 80, n = i - b * 80;
    const float* qr = q + b * 64;
    float acc = b1[n];
    #pragma unroll 8
    for (int d = 0; d < 64; ++d) acc = fmaf(qr[d], wqf[d * 80 + n], acc);
    hinit[i] = acc;
}

// ---------------------------------------------------------------------------
// Main kernel: 4 waves/block, one block per batch row. Layers 1+2 FUSED per
// wave through a wave-private LDS chunk (no block barrier between layers).
// Wave w handles 16-row tiles {w, w+4, w+8, (w==0: 12)}; keys loads are
// double-buffered across tile iterations.
// ---------------------------------------------------------------------------
__global__ __launch_bounds__(NT, 4)
void din_attn(const float* __restrict__ q, const float* __restrict__ keys,
              const int* __restrict__ klen, const float* __restrict__ hinit_g,
              const unsigned short* __restrict__ w1f,
              const unsigned short* __restrict__ w2f,
              const float* __restrict__ b2, const float* __restrict__ W3,
              const float* __restrict__ b3, float* __restrict__ out) {
    const int b = blockIdx.x, tid = threadIdx.x;
    const int l = tid & 63, wid = tid >> 6, g4 = l >> 4, ln = l & 15;

    __shared__ float qs[64];
    __shared__ float hin[80];
    __shared__ float w3s[48], b2s[48];
    __shared__ float red[256];
    __shared__ float part[4][64];
    __shared__ float wred[8];
    __shared__ unsigned short h1c[4][16 * 104];   // wave-private chunks, 13.3 KB

    if (tid < 64) qs[tid] = q[b * 64 + tid];
    if (tid < 80) hin[tid] = hinit_g[b * 80 + tid];
    if (tid < 48) {
        w3s[tid] = (tid < 40) ? W3[tid] : 0.f;
        b2s[tid] = (tid < 40) ? b2[tid] : 0.f;
    }
    if (tid >= 200) red[tid] = -INFINITY;
    __syncthreads();

    const int len = klen[b];
    const float b3v = b3[0];
    unsigned short* myh1 = h1c[wid];

    // loop-invariant register state (per wave)
    float hv[5], b2v[3], w3v[3];
    #pragma unroll
    for (int nt = 0; nt < 5; ++nt) hv[nt] = hin[nt * 16 + ln];
    #pragma unroll
    for (int nt = 0; nt < 3; ++nt) { b2v[nt] = b2s[nt * 16 + ln]; w3v[nt] = w3s[nt * 16 + ln]; }
    float4 q0  = *(const float4*)(qs + g4 * 8);
    float4 q0b = *(const float4*)(qs + g4 * 8 + 4);
    float4 q1  = *(const float4*)(qs + 32 + g4 * 8);
    float4 q1b = *(const float4*)(qs + 32 + g4 * 8 + 4);

    const int ntile = (wid == 0) ? 4 : 3;   // tiles wid, wid+4, wid+8, [12]

#define LOADK(tile_, buf_) do {                                            \
        int t_ = (tile_) * 16 + ln;                                        \
        int tc_ = t_ < 200 ? t_ : 199;                                     \
        const float* row_ = keys + ((size_t)b * 200 + tc_) * 64;           \
        buf_[0] = *(const float4*)(row_ + g4 * 8);                         \
        buf_[1] = *(const float4*)(row_ + g4 * 8 + 4);                     \
        buf_[2] = *(const float4*)(row_ + 32 + g4 * 8);                    \
        buf_[3] = *(const float4*)(row_ + 32 + g4 * 8 + 4);                \
    } while (0)

    float4 kq[2][4];
    LOADK(wid, kq[0]);

    #pragma unroll
    for (int i = 0; i < 4; ++i) {
        if (i < ntile) {
            const int tile = wid + 4 * i;
            if (i + 1 < ntile) { LOADK(tile + 4, kq[(i + 1) & 1]); }  // prefetch

            float4 a0 = kq[i & 1][0], a1 = kq[i & 1][1];
            float4 a2 = kq[i & 1][2], a3 = kq[i & 1][3];

            // ---- layer 1: [16x128]@[128x80], C-init = hinit ----
            f32x4 acc[5];
            #pragma unroll
            for (int nt = 0; nt < 5; ++nt)
                acc[nt] = (f32x4){hv[nt], hv[nt], hv[nt], hv[nt]};

            bf16x8 av[4];
            av[0] = pack8(a0, a1);               // k 0..31   (keys)
            av[1] = pack8(a2, a3);               // k 32..63
            av[2] = pack8m(a0, a1, q0, q0b);     // k 64..95  (q*k)
            av[3] = pack8m(a2, a3, q1, q1b);     // k 96..127
            #pragma unroll
            for (int s = 0; s < 4; ++s) {
                bf16x8 bfr[5];
                #pragma unroll
                for (int nt = 0; nt < 5; ++nt)
                    bfr[nt] = *(const bf16x8*)(w1f + ((s * 5 + nt) * 64 + l) * 8);
                #pragma unroll
                for (int nt = 0; nt < 5; ++nt)
                    acc[nt] = __builtin_amdgcn_mfma_f32_16x16x32_bf16(
                        av[s], bfr[nt], acc[nt], 0, 0, 0);
            }

            // ---- sigmoid -> wave-private LDS chunk (bf16) ----
            #pragma unroll
            for (int nt = 0; nt < 5; ++nt)
                #pragma unroll
                for (int r = 0; r < 4; ++r) {
                    float sg = 1.f / (1.f + __expf(-acc[nt][r]));
                    myh1[(g4 * 4 + r) * 104 + nt * 16 + ln] = b16bits(sg);
                }
            #pragma unroll
            for (int r = 0; r < 4; ++r)
                myh1[(g4 * 4 + r) * 104 + 80 + ln] = 0;   // zero pad cols 80..95

            // ---- layer 2: [16x96]@[96x48] (wave-local, no barrier) ----
            bf16x8 af0 = *(const bf16x8*)(myh1 + ln * 104 + g4 * 8);
            bf16x8 af1 = *(const bf16x8*)(myh1 + ln * 104 + 32 + g4 * 8);
            bf16x8 af2 = *(const bf16x8*)(myh1 + ln * 104 + 64 + g4 * 8);
            f32x4 acc2[3];
            #pragma unroll
            for (int nt = 0; nt < 3; ++nt)
                acc2[nt] = (f32x4){b2v[nt], b2v[nt], b2v[nt], b2v[nt]};
            #pragma unroll
            for (int nt = 0; nt < 3; ++nt) {
                bf16x8 w0 = *(const bf16x8*)(w2f + ((0 * 3 + nt) * 64 + l) * 8);
                bf16x8 w1v = *(const bf16x8*)(w2f + ((1 * 3 + nt) * 64 + l) * 8);
                bf16x8 w2v = *(const bf16x8*)(w2f + ((2 * 3 + nt) * 64 + l) * 8);
                acc2[nt] = __builtin_amdgcn_mfma_f32_16x16x32_bf16(af0, w0, acc2[nt], 0, 0, 0);
                acc2[nt] = __builtin_amdgcn_mfma_f32_16x16x32_bf16(af1, w1v, acc2[nt], 0, 0, 0);
                acc2[nt] = __builtin_amdgcn_mfma_f32_16x16x32_bf16(af2, w2v, acc2[nt], 0, 0, 0);
            }

            // ---- layer 3 + mask -> red ----
            #pragma unroll
            for (int r = 0; r < 4; ++r) {
                float p = w3v[0] / (1.f + __expf(-acc2[0][r]))
                        + w3v[1] / (1.f + __expf(-acc2[1][r]))
                        + w3v[2] / (1.f + __expf(-acc2[2][r]));
                p += __shfl_xor(p, 1); p += __shfl_xor(p, 2);
                p += __shfl_xor(p, 4); p += __shfl_xor(p, 8);
                if (ln == 0) {
                    int trow = tile * 16 + g4 * 4 + r;
                    if (trow < 200)
                        red[trow] = (trow < len) ? (p + b3v) * 0.125f
                                                 : NEG_INF_F * 0.125f;
                }
            }
        }
    }
#undef LOADK
    __syncthreads();

    // ---------------- softmax over red[0..255] (verified) ----------------
    float v = red[tid];
    float m = v;
    #pragma unroll
    for (int off = 32; off; off >>= 1) m = fmaxf(m, __shfl_xor(m, off));
    if ((tid & 63) == 0) wred[tid >> 6] = m;
    __syncthreads();
    m = fmaxf(fmaxf(wred[0], wred[1]), fmaxf(wred[2], wred[3]));
    float e = __expf(v - m);
    float s = e;
    #pragma unroll
    for (int off = 32; off; off >>= 1) s += __shfl_xor(s, off);
    if ((tid & 63) == 0) wred[4 + (tid >> 6)] = s;
    __syncthreads();
    s = wred[4] + wred[5] + wred[6] + wred[7];
    red[tid] = e / s;
    __syncthreads();

    // ---------------- output: out[b][d] = sum_t attn[t]*keys[b][t][d] ----
    {
        const int d = tid & 63, gg = tid >> 6;
        float acc = 0.f;
        const float* kb = keys + (size_t)b * T_ * D_;
        for (int tt = gg; tt < T_; tt += 4)
            acc = fmaf(red[tt], kb[tt * D_ + d], acc);
        part[gg][d] = acc;
        __syncthreads();
        if (tid < D_)
            out[b * D_ + tid] = part[0][tid] + part[1][tid] + part[2][tid] + part[3][tid];
    }
}

extern "C" void kernel_launch(void* const* d_in, const int* in_sizes, int n_in,
                              void* d_out, int out_size, void* d_ws, size_t ws_size,
                              hipStream_t stream) {
    const float* q    = (const float*)d_in[0];
    const float* keys = (const float*)d_in[1];
    const int*   kl   = (const int*)d_in[2];
    const float* W1   = (const float*)d_in[3];
    const float* b1   = (const float*)d_in[4];
    const float* W2   = (const float*)d_in[5];
    const float* b2   = (const float*)d_in[6];
    const float* W3   = (const float*)d_in[7];
    const float* b3   = (const float*)d_in[8];

    unsigned short* w1f = (unsigned short*)d_ws;            // 10240 bf16
    unsigned short* w2f = w1f + 10240;                      //  4608 bf16
    float* wqf   = (float*)((char*)d_ws + 32768);           //  5120 f32
    float* hinit = wqf + 5120;                              // 327680 f32

    fold_weights<<<(19968 + 255) / 256, 256, 0, stream>>>(W1, W2, w1f, w2f, wqf);
    hinit_kernel<<<(B_ * 80 + 255) / 256, 256, 0, stream>>>(q, wqf, b1, hinit);
    din_attn<<<B_, NT, 0, stream>>>(q, keys, kl, hinit, w1f, w2f, b2, W3, b3,
                                    (float*)d_out);
}

// Round 5
// 219.076 us; speedup vs baseline: 1.3091x; 1.3091x over previous
//
#include <hip/hip_runtime.h>
#include <math.h>

constexpr int B_ = 4096, T_ = 200, D_ = 64, NT = 256;
constexpr float NEG_INF_F = -4294967295.0f;  // float32(-2^32+1)

typedef __attribute__((ext_vector_type(8))) __bf16 bf16x8;
typedef __attribute__((ext_vector_type(4))) float f32x4;

__device__ __host__ inline unsigned short f2b_rne(float x) {
    unsigned u = __builtin_bit_cast(unsigned, x);
    u += 0x7FFF + ((u >> 16) & 1);
    return (unsigned short)(u >> 16);
}

__device__ inline unsigned short b16bits(float x) {
    return __builtin_bit_cast(unsigned short, (__bf16)x);
}

__device__ inline bf16x8 pack8(float4 lo, float4 hi) {
    bf16x8 r;
    r[0] = (__bf16)lo.x; r[1] = (__bf16)lo.y; r[2] = (__bf16)lo.z; r[3] = (__bf16)lo.w;
    r[4] = (__bf16)hi.x; r[5] = (__bf16)hi.y; r[6] = (__bf16)hi.z; r[7] = (__bf16)hi.w;
    return r;
}

__device__ inline bf16x8 pack8m(float4 lo, float4 hi, float4 ql, float4 qh) {
    bf16x8 r;
    r[0] = (__bf16)(lo.x * ql.x); r[1] = (__bf16)(lo.y * ql.y);
    r[2] = (__bf16)(lo.z * ql.z); r[3] = (__bf16)(lo.w * ql.w);
    r[4] = (__bf16)(hi.x * qh.x); r[5] = (__bf16)(hi.y * qh.y);
    r[6] = (__bf16)(hi.z * qh.z); r[7] = (__bf16)(hi.w * qh.w);
    return r;
}

// ---------------------------------------------------------------------------
// Fold weights into MFMA-fragment order (bf16). Same layouts as round 3.
// ---------------------------------------------------------------------------
__global__ void fold_weights(const float* __restrict__ W1,
                             const float* __restrict__ W2,
                             unsigned short* __restrict__ w1f,
                             unsigned short* __restrict__ w2f,
                             float* __restrict__ wqf) {
    int i = blockIdx.x * blockDim.x + threadIdx.x;
    if (i < 10240) {
        int j = i & 7, lane = (i >> 3) & 63, nt = (i >> 9) % 5, s = i / 2560;
        int k = s * 32 + (lane >> 4) * 8 + j;
        int n = nt * 16 + (lane & 15);
        float v = (k < 64) ? W1[(64 + k) * 80 + n] - W1[(128 + k) * 80 + n]
                           : W1[(192 + (k - 64)) * 80 + n];
        w1f[i] = f2b_rne(v);
    } else if (i < 14848) {
        int i2 = i - 10240;
        int j = i2 & 7, lane = (i2 >> 3) & 63, nt = (i2 >> 9) % 3, s = i2 / 1536;
        int k = s * 32 + (lane >> 4) * 8 + j;
        int n = nt * 16 + (lane & 15);
        float v = (k < 80 && n < 40) ? W2[k * 40 + n] : 0.f;
        w2f[i2] = f2b_rne(v);
    } else if (i < 19968) {
        int i3 = i - 14848;
        int n = i3 % 80, d = i3 / 80;
        wqf[i3] = W1[d * 80 + n] + W1[(128 + d) * 80 + n];
    }
}

__global__ __launch_bounds__(256)
void hinit_kernel(const float* __restrict__ q, const float* __restrict__ wqf,
                  const float* __restrict__ b1, float* __restrict__ hinit) {
    int i = blockIdx.x * blockDim.x + threadIdx.x;
    if (i >= B_ * 80) return;
    int b = i / 80, n = i - b * 80;
    const float* qr = q + b * 64;
    float acc = b1[n];
    #pragma unroll 8
    for (int d = 0; d < 64; ++d) acc = fmaf(qr[d], wqf[d * 80 + n], acc);
    hinit[i] = acc;
}

// ---------------------------------------------------------------------------
// Main kernel: 4 waves/block, one block per batch row. Layers 1+2 fused per
// wave through a wave-private LDS chunk (no block barrier between layers).
// __launch_bounds__(NT,2): round-4's (NT,4) clamped VGPR to 64 and spilled
// ~56KB/block (WRITE_SIZE 1MB->230MB); (NT,2) fits spill-free (round 3: 108).
// ---------------------------------------------------------------------------
__global__ __launch_bounds__(NT, 2)
void din_attn(const float* __restrict__ q, const float* __restrict__ keys,
              const int* __restrict__ klen, const float* __restrict__ hinit_g,
              const unsigned short* __restrict__ w1f,
              const unsigned short* __restrict__ w2f,
              const float* __restrict__ b2, const float* __restrict__ W3,
              const float* __restrict__ b3, float* __restrict__ out) {
    const int b = blockIdx.x, tid = threadIdx.x;
    const int l = tid & 63, wid = tid >> 6, g4 = l >> 4, ln = l & 15;

    __shared__ float qs[64];
    __shared__ float hin[80];
    __shared__ float w3s[48], b2s[48];
    __shared__ float red[256];
    __shared__ float part[4][64];
    __shared__ float wred[8];
    __shared__ unsigned short h1c[4][16 * 104];   // wave-private chunks, 13.3 KB

    if (tid < 64) qs[tid] = q[b * 64 + tid];
    if (tid < 80) hin[tid] = hinit_g[b * 80 + tid];
    if (tid < 48) {
        w3s[tid] = (tid < 40) ? W3[tid] : 0.f;
        b2s[tid] = (tid < 40) ? b2[tid] : 0.f;
    }
    if (tid >= 200) red[tid] = -INFINITY;
    __syncthreads();

    const int len = klen[b];
    const float b3v = b3[0];
    unsigned short* myh1 = h1c[wid];

    // zero pad cols 80..95 of the wave chunk ONCE (tile-invariant)
    #pragma unroll
    for (int r = 0; r < 4; ++r)
        myh1[(g4 * 4 + r) * 104 + 80 + ln] = 0;

    // loop-invariant register state (per wave)
    float hv[5], b2v[3], w3v[3];
    #pragma unroll
    for (int nt = 0; nt < 5; ++nt) hv[nt] = hin[nt * 16 + ln];
    #pragma unroll
    for (int nt = 0; nt < 3; ++nt) { b2v[nt] = b2s[nt * 16 + ln]; w3v[nt] = w3s[nt * 16 + ln]; }
    float4 q0  = *(const float4*)(qs + g4 * 8);
    float4 q0b = *(const float4*)(qs + g4 * 8 + 4);
    float4 q1  = *(const float4*)(qs + 32 + g4 * 8);
    float4 q1b = *(const float4*)(qs + 32 + g4 * 8 + 4);

    const int ntile = (wid == 0) ? 4 : 3;   // tiles wid, wid+4, wid+8, [12]

#define LOADK(tile_, buf_) do {                                            \
        int t_ = (tile_) * 16 + ln;                                        \
        int tc_ = t_ < 200 ? t_ : 199;                                     \
        const float* row_ = keys + ((size_t)b * 200 + tc_) * 64;           \
        buf_[0] = *(const float4*)(row_ + g4 * 8);                         \
        buf_[1] = *(const float4*)(row_ + g4 * 8 + 4);                     \
        buf_[2] = *(const float4*)(row_ + 32 + g4 * 8);                    \
        buf_[3] = *(const float4*)(row_ + 32 + g4 * 8 + 4);                \
    } while (0)

    float4 kq[2][4];
    LOADK(wid, kq[0]);

    #pragma unroll
    for (int i = 0; i < 4; ++i) {
        if (i < ntile) {
            const int tile = wid + 4 * i;
            if (i + 1 < ntile) { LOADK(tile + 4, kq[(i + 1) & 1]); }  // prefetch

            float4 a0 = kq[i & 1][0], a1 = kq[i & 1][1];
            float4 a2 = kq[i & 1][2], a3 = kq[i & 1][3];

            // ---- layer 1: [16x128]@[128x80], C-init = hinit ----
            f32x4 acc[5];
            #pragma unroll
            for (int nt = 0; nt < 5; ++nt)
                acc[nt] = (f32x4){hv[nt], hv[nt], hv[nt], hv[nt]};

            bf16x8 av[4];
            av[0] = pack8(a0, a1);               // k 0..31   (keys)
            av[1] = pack8(a2, a3);               // k 32..63
            av[2] = pack8m(a0, a1, q0, q0b);     // k 64..95  (q*k)
            av[3] = pack8m(a2, a3, q1, q1b);     // k 96..127
            #pragma unroll
            for (int s = 0; s < 4; ++s) {
                bf16x8 bfr[5];
                #pragma unroll
                for (int nt = 0; nt < 5; ++nt)
                    bfr[nt] = *(const bf16x8*)(w1f + ((s * 5 + nt) * 64 + l) * 8);
                #pragma unroll
                for (int nt = 0; nt < 5; ++nt)
                    acc[nt] = __builtin_amdgcn_mfma_f32_16x16x32_bf16(
                        av[s], bfr[nt], acc[nt], 0, 0, 0);
            }

            // ---- sigmoid -> wave-private LDS chunk (bf16) ----
            #pragma unroll
            for (int nt = 0; nt < 5; ++nt)
                #pragma unroll
                for (int r = 0; r < 4; ++r) {
                    float sg = 1.f / (1.f + __expf(-acc[nt][r]));
                    myh1[(g4 * 4 + r) * 104 + nt * 16 + ln] = b16bits(sg);
                }

            // ---- layer 2: [16x96]@[96x48] (wave-local, no barrier) ----
            bf16x8 af0 = *(const bf16x8*)(myh1 + ln * 104 + g4 * 8);
            bf16x8 af1 = *(const bf16x8*)(myh1 + ln * 104 + 32 + g4 * 8);
            bf16x8 af2 = *(const bf16x8*)(myh1 + ln * 104 + 64 + g4 * 8);
            f32x4 acc2[3];
            #pragma unroll
            for (int nt = 0; nt < 3; ++nt)
                acc2[nt] = (f32x4){b2v[nt], b2v[nt], b2v[nt], b2v[nt]};
            #pragma unroll
            for (int nt = 0; nt < 3; ++nt) {
                bf16x8 w0 = *(const bf16x8*)(w2f + ((0 * 3 + nt) * 64 + l) * 8);
                bf16x8 w1v = *(const bf16x8*)(w2f + ((1 * 3 + nt) * 64 + l) * 8);
                bf16x8 w2v = *(const bf16x8*)(w2f + ((2 * 3 + nt) * 64 + l) * 8);
                acc2[nt] = __builtin_amdgcn_mfma_f32_16x16x32_bf16(af0, w0, acc2[nt], 0, 0, 0);
                acc2[nt] = __builtin_amdgcn_mfma_f32_16x16x32_bf16(af1, w1v, acc2[nt], 0, 0, 0);
                acc2[nt] = __builtin_amdgcn_mfma_f32_16x16x32_bf16(af2, w2v, acc2[nt], 0, 0, 0);
            }

            // ---- layer 3 + mask -> red ----
            #pragma unroll
            for (int r = 0; r < 4; ++r) {
                float p = w3v[0] / (1.f + __expf(-acc2[0][r]))
                        + w3v[1] / (1.f + __expf(-acc2[1][r]))
                        + w3v[2] / (1.f + __expf(-acc2[2][r]));
                p += __shfl_xor(p, 1); p += __shfl_xor(p, 2);
                p += __shfl_xor(p, 4); p += __shfl_xor(p, 8);
                if (ln == 0) {
                    int trow = tile * 16 + g4 * 4 + r;
                    if (trow < 200)
                        red[trow] = (trow < len) ? (p + b3v) * 0.125f
                                                 : NEG_INF_F * 0.125f;
                }
            }
        }
    }
#undef LOADK
    __syncthreads();

    // ---------------- softmax over red[0..255] (verified) ----------------
    float v = red[tid];
    float m = v;
    #pragma unroll
    for (int off = 32; off; off >>= 1) m = fmaxf(m, __shfl_xor(m, off));
    if ((tid & 63) == 0) wred[tid >> 6] = m;
    __syncthreads();
    m = fmaxf(fmaxf(wred[0], wred[1]), fmaxf(wred[2], wred[3]));
    float e = __expf(v - m);
    float s = e;
    #pragma unroll
    for (int off = 32; off; off >>= 1) s += __shfl_xor(s, off);
    if ((tid & 63) == 0) wred[4 + (tid >> 6)] = s;
    __syncthreads();
    s = wred[4] + wred[5] + wred[6] + wred[7];
    red[tid] = e / s;
    __syncthreads();

    // ---------------- output: out[b][d] = sum_t attn[t]*keys[b][t][d] ----
    {
        const int d = tid & 63, gg = tid >> 6;
        float acc = 0.f;
        const float* kb = keys + (size_t)b * T_ * D_;
        for (int tt = gg; tt < T_; tt += 4)
            acc = fmaf(red[tt], kb[tt * D_ + d], acc);
        part[gg][d] = acc;
        __syncthreads();
        if (tid < D_)
            out[b * D_ + tid] = part[0][tid] + part[1][tid] + part[2][tid] + part[3][tid];
    }
}

extern "C" void kernel_launch(void* const* d_in, const int* in_sizes, int n_in,
                              void* d_out, int out_size, void* d_ws, size_t ws_size,
                              hipStream_t stream) {
    const float* q    = (const float*)d_in[0];
    const float* keys = (const float*)d_in[1];
    const int*   kl   = (const int*)d_in[2];
    const float* W1   = (const float*)d_in[3];
    const float* b1   = (const float*)d_in[4];
    const float* W2   = (const float*)d_in[5];
    const float* b2   = (const float*)d_in[6];
    const float* W3   = (const float*)d_in[7];
    const float* b3   = (const float*)d_in[8];

    unsigned short* w1f = (unsigned short*)d_ws;            // 10240 bf16
    unsigned short* w2f = w1f + 10240;                      //  4608 bf16
    float* wqf   = (float*)((char*)d_ws + 32768);           //  5120 f32
    float* hinit = wqf + 5120;                              // 327680 f32

    fold_weights<<<(19968 + 255) / 256, 256, 0, stream>>>(W1, W2, w1f, w2f, wqf);
    hinit_kernel<<<(B_ * 80 + 255) / 256, 256, 0, stream>>>(q, wqf, b1, hinit);
    din_attn<<<B_, NT, 0, stream>>>(q, keys, kl, hinit, w1f, w2f, b2, W3, b3,
                                    (float*)d_out);
}

// Round 6
// 113.178 us; speedup vs baseline: 2.5340x; 1.9357x over previous
//
#include <hip/hip_runtime.h>
#include <math.h>

constexpr int B_ = 4096, T_ = 200, D_ = 64, NT = 256;
constexpr float NEG_INF_F = -4294967295.0f;  // float32(-2^32+1)

typedef __attribute__((ext_vector_type(8))) __bf16 bf16x8;
typedef __attribute__((ext_vector_type(4))) float f32x4;

__device__ __host__ inline unsigned short f2b_rne(float x) {
    unsigned u = __builtin_bit_cast(unsigned, x);
    u += 0x7FFF + ((u >> 16) & 1);
    return (unsigned short)(u >> 16);
}

__device__ inline unsigned short b16bits(float x) {
    return __builtin_bit_cast(unsigned short, (__bf16)x);
}

__device__ inline bf16x8 pack8(float4 lo, float4 hi) {
    bf16x8 r;
    r[0] = (__bf16)lo.x; r[1] = (__bf16)lo.y; r[2] = (__bf16)lo.z; r[3] = (__bf16)lo.w;
    r[4] = (__bf16)hi.x; r[5] = (__bf16)hi.y; r[6] = (__bf16)hi.z; r[7] = (__bf16)hi.w;
    return r;
}

__device__ inline bf16x8 pack8m(float4 lo, float4 hi, float4 ql, float4 qh) {
    bf16x8 r;
    r[0] = (__bf16)(lo.x * ql.x); r[1] = (__bf16)(lo.y * ql.y);
    r[2] = (__bf16)(lo.z * ql.z); r[3] = (__bf16)(lo.w * ql.w);
    r[4] = (__bf16)(hi.x * qh.x); r[5] = (__bf16)(hi.y * qh.y);
    r[6] = (__bf16)(hi.z * qh.z); r[7] = (__bf16)(hi.w * qh.w);
    return r;
}

// ---------------------------------------------------------------------------
// Fold weights into MFMA-fragment order (bf16). Same layouts as round 3.
// ---------------------------------------------------------------------------
__global__ void fold_weights(const float* __restrict__ W1,
                             const float* __restrict__ W2,
                             unsigned short* __restrict__ w1f,
                             unsigned short* __restrict__ w2f,
                             float* __restrict__ wqf) {
    int i = blockIdx.x * blockDim.x + threadIdx.x;
    if (i < 10240) {
        int j = i & 7, lane = (i >> 3) & 63, nt = (i >> 9) % 5, s = i / 2560;
        int k = s * 32 + (lane >> 4) * 8 + j;
        int n = nt * 16 + (lane & 15);
        float v = (k < 64) ? W1[(64 + k) * 80 + n] - W1[(128 + k) * 80 + n]
                           : W1[(192 + (k - 64)) * 80 + n];
        w1f[i] = f2b_rne(v);
    } else if (i < 14848) {
        int i2 = i - 10240;
        int j = i2 & 7, lane = (i2 >> 3) & 63, nt = (i2 >> 9) % 3, s = i2 / 1536;
        int k = s * 32 + (lane >> 4) * 8 + j;
        int n = nt * 16 + (lane & 15);
        float v = (k < 80 && n < 40) ? W2[k * 40 + n] : 0.f;
        w2f[i2] = f2b_rne(v);
    } else if (i < 19968) {
        int i3 = i - 14848;
        int n = i3 % 80, d = i3 / 80;
        wqf[i3] = W1[d * 80 + n] + W1[(128 + d) * 80 + n];
    }
}

__global__ __launch_bounds__(256)
void hinit_kernel(const float* __restrict__ q, const float* __restrict__ wqf,
                  const float* __restrict__ b1, float* __restrict__ hinit) {
    int i = blockIdx.x * blockDim.x + threadIdx.x;
    if (i >= B_ * 80) return;
    int b = i / 80, n = i - b * 80;
    const float* qr = q + b * 64;
    float acc = b1[n];
    #pragma unroll 8
    for (int d = 0; d < 64; ++d) acc = fmaf(qr[d], wqf[d * 80 + n], acc);
    hinit[i] = acc;
}

// ---------------------------------------------------------------------------
// Main kernel: ONE WAVE = ONE BATCH ROW (4 rows/block), zero barriers in the
// hot path. Grid = 1024 blocks = 4/CU -> whole problem resident; every wave
// keeps HBM loads in flight (round-5 was latency-bound at ~13 lines/CU).
// W1 frags staged in LDS once per block; W2 frags from global (L1-resident).
// ---------------------------------------------------------------------------
__global__ __launch_bounds__(NT, 2)
void din_attn(const float* __restrict__ q, const float* __restrict__ keys,
              const int* __restrict__ klen, const float* __restrict__ hinit_g,
              const unsigned short* __restrict__ w1f,
              const unsigned short* __restrict__ w2f,
              const float* __restrict__ b2, const float* __restrict__ W3,
              const float* __restrict__ b3, float* __restrict__ out) {
    const int tid = threadIdx.x;
    const int l = tid & 63, wid = tid >> 6, g4 = l >> 4, ln = l & 15;
    const int b = blockIdx.x * 4 + wid;

    alignas(16) __shared__ unsigned short w1s[10240];      // 20.5 KB: W1 frags
    alignas(16) __shared__ unsigned short h1c[4][16 * 104]; // 13.3 KB wave-priv
    __shared__ float red[4][256];                           // 4 KB logits/attn

    // one-time cooperative stage of W1 frags -> LDS (5 x 16B per thread)
    #pragma unroll
    for (int j = 0; j < 5; ++j) {
        int idx = (j * 256 + tid) * 8;
        *(float4*)&w1s[idx] = *(const float4*)&w1f[idx];
    }
    float* myred = red[wid];
    unsigned short* myh1 = h1c[wid];
    if (l >= 8) myred[192 + l] = -INFINITY;   // pad rows 200..255
    #pragma unroll
    for (int r = 0; r < 4; ++r)
        myh1[(g4 * 4 + r) * 104 + 80 + ln] = 0;  // zero pad cols 80..95 once
    __syncthreads();   // w1s ready — the ONLY block barrier

    const int len = klen[b];
    const float b3v = b3[0];

    // per-wave loop-invariant register state
    float hv[5], b2v[3], w3v[3];
    const float* hb = hinit_g + b * 80;
    #pragma unroll
    for (int nt = 0; nt < 5; ++nt) hv[nt] = hb[nt * 16 + ln];
    #pragma unroll
    for (int nt = 0; nt < 3; ++nt) {
        int idx = nt * 16 + ln;
        b2v[nt] = (idx < 40) ? b2[idx] : 0.f;
        w3v[nt] = (idx < 40) ? W3[idx] : 0.f;
    }
    const float* qb = q + b * 64;
    float4 q0  = *(const float4*)(qb + g4 * 8);
    float4 q0b = *(const float4*)(qb + g4 * 8 + 4);
    float4 q1  = *(const float4*)(qb + 32 + g4 * 8);
    float4 q1b = *(const float4*)(qb + 32 + g4 * 8 + 4);

    const float* kb = keys + (size_t)b * 200 * 64;

#define LOADK(tile_, B0_, B1_, B2_, B3_) do {                              \
        int t_ = (tile_) * 16 + ln;                                        \
        int tc_ = t_ < 200 ? t_ : 199;                                     \
        const float* row_ = kb + tc_ * 64;                                 \
        B0_ = *(const float4*)(row_ + g4 * 8);                             \
        B1_ = *(const float4*)(row_ + g4 * 8 + 4);                         \
        B2_ = *(const float4*)(row_ + 32 + g4 * 8);                        \
        B3_ = *(const float4*)(row_ + 32 + g4 * 8 + 4);                    \
    } while (0)

#define COMPUTE(tile_, K0_, K1_, K2_, K3_) do {                            \
        f32x4 acc[5];                                                      \
        _Pragma("unroll")                                                  \
        for (int nt = 0; nt < 5; ++nt)                                     \
            acc[nt] = (f32x4){hv[nt], hv[nt], hv[nt], hv[nt]};             \
        bf16x8 av0 = pack8(K0_, K1_);                                      \
        bf16x8 av1 = pack8(K2_, K3_);                                      \
        bf16x8 av2 = pack8m(K0_, K1_, q0, q0b);                            \
        bf16x8 av3 = pack8m(K2_, K3_, q1, q1b);                            \
        _Pragma("unroll")                                                  \
        for (int s = 0; s < 4; ++s) {                                      \
            bf16x8 a_ = (s == 0) ? av0 : (s == 1) ? av1                    \
                      : (s == 2) ? av2 : av3;                              \
            _Pragma("unroll")                                              \
            for (int nt = 0; nt < 5; ++nt) {                               \
                bf16x8 bfr = *(const bf16x8*)&w1s[((s * 5 + nt) * 64 + l) * 8]; \
                acc[nt] = __builtin_amdgcn_mfma_f32_16x16x32_bf16(         \
                    a_, bfr, acc[nt], 0, 0, 0);                            \
            }                                                              \
        }                                                                  \
        _Pragma("unroll")                                                  \
        for (int nt = 0; nt < 5; ++nt)                                     \
            _Pragma("unroll")                                              \
            for (int r = 0; r < 4; ++r) {                                  \
                float sg = 1.f / (1.f + __expf(-acc[nt][r]));              \
                myh1[(g4 * 4 + r) * 104 + nt * 16 + ln] = b16bits(sg);     \
            }                                                              \
        bf16x8 af0 = *(const bf16x8*)(myh1 + ln * 104 + g4 * 8);           \
        bf16x8 af1 = *(const bf16x8*)(myh1 + ln * 104 + 32 + g4 * 8);      \
        bf16x8 af2 = *(const bf16x8*)(myh1 + ln * 104 + 64 + g4 * 8);      \
        f32x4 acc2[3];                                                     \
        _Pragma("unroll")                                                  \
        for (int nt = 0; nt < 3; ++nt)                                     \
            acc2[nt] = (f32x4){b2v[nt], b2v[nt], b2v[nt], b2v[nt]};        \
        _Pragma("unroll")                                                  \
        for (int nt = 0; nt < 3; ++nt) {                                   \
            bf16x8 w0_ = *(const bf16x8*)(w2f + ((0 * 3 + nt) * 64 + l) * 8); \
            bf16x8 w1_ = *(const bf16x8*)(w2f + ((1 * 3 + nt) * 64 + l) * 8); \
            bf16x8 w2_ = *(const bf16x8*)(w2f + ((2 * 3 + nt) * 64 + l) * 8); \
            acc2[nt] = __builtin_amdgcn_mfma_f32_16x16x32_bf16(af0, w0_, acc2[nt], 0, 0, 0); \
            acc2[nt] = __builtin_amdgcn_mfma_f32_16x16x32_bf16(af1, w1_, acc2[nt], 0, 0, 0); \
            acc2[nt] = __builtin_amdgcn_mfma_f32_16x16x32_bf16(af2, w2_, acc2[nt], 0, 0, 0); \
        }                                                                  \
        _Pragma("unroll")                                                  \
        for (int r = 0; r < 4; ++r) {                                      \
            float p = w3v[0] / (1.f + __expf(-acc2[0][r]))                 \
                    + w3v[1] / (1.f + __expf(-acc2[1][r]))                 \
                    + w3v[2] / (1.f + __expf(-acc2[2][r]));                \
            p += __shfl_xor(p, 1); p += __shfl_xor(p, 2);                  \
            p += __shfl_xor(p, 4); p += __shfl_xor(p, 8);                  \
            if (ln == 0) {                                                 \
                int trow = (tile_) * 16 + g4 * 4 + r;                      \
                if (trow < 200)                                            \
                    myred[trow] = (trow < len) ? (p + b3v) * 0.125f        \
                                               : NEG_INF_F * 0.125f;       \
            }                                                              \
        }                                                                  \
    } while (0)

    // 13 tiles, 2-deep ping-pong prefetch, runtime loop (keeps VGPR in check)
    float4 A0, A1, A2, A3, C0, C1, C2, C3;
    LOADK(0, A0, A1, A2, A3);
    #pragma unroll 1
    for (int it = 0; it < 6; ++it) {
        int t0 = 2 * it;
        LOADK(t0 + 1, C0, C1, C2, C3);
        COMPUTE(t0, A0, A1, A2, A3);
        LOADK(t0 + 2, A0, A1, A2, A3);
        COMPUTE(t0 + 1, C0, C1, C2, C3);
    }
    COMPUTE(12, A0, A1, A2, A3);
#undef LOADK
#undef COMPUTE

    // ---------------- wave-local softmax over myred[0..255] ----------------
    float v0 = myred[l], v1 = myred[64 + l], v2 = myred[128 + l], v3 = myred[192 + l];
    float m = fmaxf(fmaxf(v0, v1), fmaxf(v2, v3));
    #pragma unroll
    for (int off = 32; off; off >>= 1) m = fmaxf(m, __shfl_xor(m, off));
    float e0 = __expf(v0 - m), e1 = __expf(v1 - m);
    float e2 = __expf(v2 - m), e3 = __expf(v3 - m);
    float s = (e0 + e1) + (e2 + e3);
    #pragma unroll
    for (int off = 32; off; off >>= 1) s += __shfl_xor(s, off);
    myred[l] = e0 / s; myred[64 + l] = e1 / s;
    myred[128 + l] = e2 / s; myred[192 + l] = e3 / s;

    // ---------------- output: out[b][l] = sum_t attn[t]*keys[b][t][l] ------
    float a0 = 0.f, a1 = 0.f, a2 = 0.f, a3 = 0.f;
    #pragma unroll 2
    for (int t = 0; t < 200; t += 4) {
        a0 = fmaf(myred[t],     kb[(t)     * 64 + l], a0);
        a1 = fmaf(myred[t + 1], kb[(t + 1) * 64 + l], a1);
        a2 = fmaf(myred[t + 2], kb[(t + 2) * 64 + l], a2);
        a3 = fmaf(myred[t + 3], kb[(t + 3) * 64 + l], a3);
    }
    out[b * 64 + l] = (a0 + a1) + (a2 + a3);
}

extern "C" void kernel_launch(void* const* d_in, const int* in_sizes, int n_in,
                              void* d_out, int out_size, void* d_ws, size_t ws_size,
                              hipStream_t stream) {
    const float* q    = (const float*)d_in[0];
    const float* keys = (const float*)d_in[1];
    const int*   kl   = (const int*)d_in[2];
    const float* W1   = (const float*)d_in[3];
    const float* b1   = (const float*)d_in[4];
    const float* W2   = (const float*)d_in[5];
    const float* b2   = (const float*)d_in[6];
    const float* W3   = (const float*)d_in[7];
    const float* b3   = (const float*)d_in[8];

    unsigned short* w1f = (unsigned short*)d_ws;            // 10240 bf16
    unsigned short* w2f = w1f + 10240;                      //  4608 bf16
    float* wqf   = (float*)((char*)d_ws + 32768);           //  5120 f32
    float* hinit = wqf + 5120;                              // 327680 f32

    fold_weights<<<(19968 + 255) / 256, 256, 0, stream>>>(W1, W2, w1f, w2f, wqf);
    hinit_kernel<<<(B_ * 80 + 255) / 256, 256, 0, stream>>>(q, wqf, b1, hinit);
    din_attn<<<B_ / 4, NT, 0, stream>>>(q, keys, kl, hinit, w1f, w2f, b2, W3, b3,
                                        (float*)d_out);
}